// Round 20
// baseline (557.119 us; speedup 1.0000x reference)
//
#include <hip/hip_runtime.h>
#include <hip/hip_bf16.h>
#include <math.h>

typedef unsigned short ushort_t;
typedef unsigned int uint_t;

// Problem constants: S=32 scenes, N=32 peds, B=1024, E=64, H=128, PRE=512, MLP_D=1024, T=12
// All float inputs are f32; output is f32.
#define T_ 12

// ---- ws layout (float offsets) ----
#define F_LP0   0         // last_pos      (2048)
#define F_LPR   2048      // last_pos_rel  (2048)
#define F_H0    4096      // h0            (131072)
#define F_C0    135168    // c0            (131072)
#define F_WSP   266240    // Wsp (64,2)
#define F_BSP   266368    // bsp (64)
#define F_WIH   266432    // Wih (512,64)
#define F_WHH   299200    // Whh (512,128)
#define F_BIH   364736
#define F_BHH   365248
#define F_WH2P  365760    // (2,128)
#define F_BH2P  366016    // (2)
#define F_WPE   366032    // (64,2)
#define F_BPE   366160    // (64)
#define F_WP1   366224    // (512,192)
#define F_BP1   464528    // (512)
#define F_WP2   465040    // (128,512)
#define F_BP2   530576    // (128)
#define F_WM1   530704    // (1024,256)
#define F_BM1   792848    // (1024)
#define F_WM2   793872    // (128,1024)
#define F_BM2   924944    // (128)
// State / derived (bf16 activations to keep L2 working set < 4MB/XCD):
#define OFF_HC   925072   // initial hidden f32 (B,128) [k_lstm0 read only]
#define OFF_LPB  1056144  // LP parity-1 (B,2)
#define OFF_C    1187216  // cell f32 (B,128), row-local RMW
#define OFF_XB   1318288  // lstm input bf16 (B,64) = 65536 ushorts
#define OFF_LP   1383824  // LP parity-0 (B,2)
#define OFF_HP   1385872  // HP bf16 ping-pong: 2 x (1024x512) ushorts = 524288 floats
#define OFF_A2   1910160  // (2,512)
#define OFF_B512 1911184  // (512)
#define OFF_W2F  1911696  // Wp2 bf16 B-frag pack (65536 ushorts)
#define OFF_HLB  1977232  // lstm hidden bf16 (B,128) = 131072 ushorts
#define OFF_HPF  2108304  // Wp1b B-frag pack (65536 ushorts)
#define OFF_M1F  2141072  // Wm1 B-frag pack (262144 ushorts)
#define OFF_M2F  2272144  // Wm2 B-frag pack (131072 ushorts)
#define OFF_BG   2337680  // gate bias bih+bhh (512)
#define OFF_LF   2338192  // Wih|Whh B-frag pack (98304 ushorts = 49152 floats)
// total ~2387344 floats = ~9.55 MB of d_ws

typedef __attribute__((ext_vector_type(8))) short short8v;   // 8 bf16 (4 VGPRs)
typedef __attribute__((ext_vector_type(4))) float f32x4;

__device__ __forceinline__ float sigf(float x){ return 1.0f/(1.0f+expf(-x)); }
__device__ __forceinline__ uint_t f2b(float f){  // RNE f32->bf16 (bits in low 16)
    uint_t u = __float_as_uint(f);
    return (u + 0x7FFFu + ((u >> 16) & 1u)) >> 16;
}
__device__ __forceinline__ float blo(uint_t u){ union{uint_t i; float f;} v; v.i=u<<16; return v.f; }
__device__ __forceinline__ float bhi(uint_t u){ union{uint_t i; float f;} v; v.i=u&0xffff0000u; return v.f; }

struct Ptrs { const void* p[22]; };

// ---- k_step LDS layout (59776 B); block owns 4 rows (rb = bid*4), scene s = bid>>3 ----
// 512 threads = 8 waves, 1 block/CU.
// R_A     0..32768 : pool a1b (32x512 bf16 swz) / mlp y1 (16x1024 swz) / lstm gates (4x512 f32)
// R_B 32768..40960 : pool A2s (f32x4[256]) / mlp at (16x256 swz) / lstm h2s (4x128)
// R_C 40960..45056 : lstm h2b (16x128 bf16 swz; rows 0-3 valid)
// R_D 45056..45184 : lstm relsh (4x2 f32)
// R_E 45184..45440 : pool lpS (64 f32)
// R_F 45440..51584 : lstm atile (16x192 bf16 swz; rows 0-3 valid, rest zero)
// R_G 51584..59776 : pool php (4x128 f32) / mlp hc out (4x128 f32)
#define SM_BYTES 59776

// ---------------- merged setup: conv copy | init | B-frag packs (+A2/B512/BG) ----------------
__global__ __launch_bounds__(256) void k_setup(Ptrs ptrs, float* __restrict__ ws)
{
    const int bid = blockIdx.x, tid = threadIdx.x;

    if (bid < 3614) {   // ---- conv: copy all f32 inputs into ws ----
        const int cums[22] = {0,2048,4096,135168,266240,266368,266432,299200,364736,
                              365248,365760,366016,366018,366146,366210,464514,465026,
                              530562,530690,792834,793858,924930};
        const int dof[22]  = {F_LP0,F_LPR,F_H0,F_C0,F_WSP,F_BSP,F_WIH,F_WHH,F_BIH,F_BHH,
                              F_WH2P,F_BH2P,F_WPE,F_BPE,F_WP1,F_BP1,F_WP2,F_BP2,F_WM1,
                              F_BM1,F_WM2,F_BM2};
        const int TOTAL = 925058;
        int g = bid*256 + tid;
        if (g < TOTAL) {
            int t = 0;
            #pragma unroll
            for (int i = 1; i < 22; i++) t += (g >= cums[i]);
            int li = g - cums[t];
            ws[dof[t] + li] = ((const float*)ptrs.p[t])[li];
        }
        return;
    }
    if (bid < 4638) {   // ---- init: h,c copy; x0 (bf16); lp parity-0 ----
        const int b = bid - 3614;
        if (tid < 128) {
            ws[OFF_HC + b*128 + tid] = ((const float*)ptrs.p[2])[b*128 + tid];
            ws[OFF_C  + b*128 + tid] = ((const float*)ptrs.p[3])[b*128 + tid];
            if (tid < 64) {
                const float* lpr = (const float*)ptrs.p[1];
                const float* Wsp = (const float*)ptrs.p[4];
                const float* bsp = (const float*)ptrs.p[5];
                float p0 = lpr[b*2], p1 = lpr[b*2 + 1];
                float xv = p0*Wsp[tid*2] + p1*Wsp[tid*2+1] + bsp[tid];
                ((ushort_t*)(ws + OFF_XB))[b*64 + tid] = (ushort_t)f2b(xv);
            }
            if (tid < 2) ws[OFF_LP + b*2 + tid] = ((const float*)ptrs.p[0])[b*2 + tid];
        }
        return;
    }
    // ---- packs (+fold) ----
    const int g = (bid - 4638)*256 + tid;
    const float* Wih = (const float*)ptrs.p[6];
    const float* Whh = (const float*)ptrs.p[7];
    const float* Wp1 = (const float*)ptrs.p[14];
    if (g < 512) {      // A2/B512/BG
        const int k = g;
        const float* Wpe = (const float*)ptrs.p[12];
        const float* bpe = (const float*)ptrs.p[13];
        float a0 = 0.f, a1 = 0.f, bb = 0.f;
        for (int e = 0; e < 64; e++) {
            float w = Wp1[k*192 + e];
            a0 += Wpe[e*2 + 0] * w;
            a1 += Wpe[e*2 + 1] * w;
            bb += bpe[e]       * w;
        }
        ws[OFF_A2 + k]       = a0;
        ws[OFF_A2 + 512 + k] = a1;
        ws[OFF_B512 + k]     = bb + ((const float*)ptrs.p[15])[k];
        ws[OFF_BG + k]       = ((const float*)ptrs.p[8])[k] + ((const float*)ptrs.p[9])[k];
    }
    if (g >= 622592) return;
    const int cums[6] = {0,65536,131072,393216,524288,622592};
    int rgn = 0;
    #pragma unroll
    for (int i = 1; i < 5; i++) rgn += (g >= cums[i]);
    const int li = g - cums[rgn];
    const int Ks[5]   = {512, 128, 256, 1024, 192};
    const int strd[5] = {512, 192, 256, 1024, 0};
    const int coff[5] = {0, 64, 0, 0, 0};
    const int dst[5]  = {OFF_W2F, OFF_HPF, OFF_M1F, OFF_M2F, OFF_LF};
    const float* srcs[5] = {(const float*)ptrs.p[16], Wp1, (const float*)ptrs.p[18],
                            (const float*)ptrs.p[20], 0};
    const int K = Ks[rgn];
    const int i = li & 7, lane = (li >> 3) & 63, rest = li >> 9;
    const int nkk = K >> 5, kk = rest % nkk, nt = rest / nkk;
    const int n = nt*16 + (lane & 15);
    const int k = kk*32 + ((lane >> 4) << 3) + i;
    float v;
    if (rgn == 4) v = (k < 64) ? Wih[n*64 + k] : Whh[n*128 + (k - 64)];
    else          v = srcs[rgn][n*strd[rgn] + coff[rgn] + k];
    ((ushort_t*)(ws + dst[rgn]))[li] = (ushort_t)f2b(v);
}

// ---------------- LSTM step for 4 rows, 512 threads (8 waves split N). ----------------
// X/HL activations in bf16 (consumed only as bf16; rounding at write == at read).
__device__ void lstm_step4(float* __restrict__ ws, float* __restrict__ out, char* smem,
                           int rb, int tstep, const float* hc_base, int hc_row0,
                           const float* __restrict__ LPr, float* __restrict__ LPw,
                           ushort_t* __restrict__ HPw, int do_next)
{
    float*    gates = (float*)smem;                 // R_A [4][512]
    float*    h2s   = (float*)(smem + 32768);       // R_B [4][128]
    ushort_t* h2b   = (ushort_t*)(smem + 40960);    // R_C [16x128 swz]
    float*    relsh = (float*)(smem + 45056);       // R_D [4][2]
    ushort_t* atile = (ushort_t*)(smem + 45440);    // R_F [16x192 swz]
    const int tid = threadIdx.x;
    ushort_t* XB  = (ushort_t*)(ws + OFF_XB);
    ushort_t* HLB = (ushort_t*)(ws + OFF_HLB);
    float* C = ws + OFF_C;

    // stage A rows 0-3 = [X(64,bf16)|hc(128,f32)]; rows 4-15 zero
    if (tid < 384) {
        const int idx = tid;
        const int r = idx / 24, k8 = idx - r*24, k = k8*8;
        uint4 val;
        if (r < 4) {
            if (k < 64) {
                val = *(const uint4*)&XB[(rb + r)*64 + k];   // bf16 copy, no convert
            } else {
                const float* src = hc_base + (hc_row0 + r)*128 + (k - 64);
                float4 f0 = ((const float4*)src)[0];
                float4 f1 = ((const float4*)src)[1];
                val.x = f2b(f0.x) | (f2b(f0.y) << 16);
                val.y = f2b(f0.z) | (f2b(f0.w) << 16);
                val.z = f2b(f1.x) | (f2b(f1.y) << 16);
                val.w = f2b(f1.z) | (f2b(f1.w) << 16);
            }
        } else {
            val = (uint4){0u,0u,0u,0u};
        }
        *(uint4*)&atile[(r*192 + k) ^ ((r & 7) << 3)] = val;
    }
    __syncthreads();

    const int lane = tid & 63, w = tid >> 6;        // w in 0..7
    const int arow = lane & 15, kch = (lane >> 4) * 8;

    short8v afr[6];
    #pragma unroll
    for (int kk = 0; kk < 6; kk++)
        afr[kk] = *(const short8v*)&atile[(arow*192 + kk*32 + kch) ^ ((arow & 7) << 3)];
    __syncthreads();

    // gates MFMA: [4(pad16)][192] @ [512][192]^T, 8 waves x 4 ct
    const ushort_t* LF = (const ushort_t*)(ws + OFF_LF);
    #pragma unroll
    for (int ct = 0; ct < 4; ct++) {
        const int ntg = w*4 + ct;
        f32x4 acc = (f32x4){0.f,0.f,0.f,0.f};
        #pragma unroll
        for (int kk = 0; kk < 6; kk++) {
            short8v b = *(const short8v*)&LF[((ntg*6 + kk)*64 + lane)*8];
            acc = __builtin_amdgcn_mfma_f32_16x16x32_bf16(afr[kk], b, acc, 0, 0, 0);
        }
        if (lane < 16) {   // C rows 0-3 (row = reg)
            const int col = ntg*16 + lane;
            const float bb = ws[OFF_BG + col];
            #pragma unroll
            for (int reg = 0; reg < 4; reg++)
                gates[reg*512 + col] = acc[reg] + bb;
        }
    }
    __syncthreads();

    // pointwise: 4 rows x 128 cols = 512 items, 1/thread
    {
        const int r = tid >> 7, hc2 = tid & 127, gr = rb + r;
        float gi = gates[r*512 + hc2];
        float gf = gates[r*512 + 128 + hc2];
        float gg = gates[r*512 + 256 + hc2];
        float go = gates[r*512 + 384 + hc2];
        float c2 = sigf(gf)*C[gr*128 + hc2] + sigf(gi)*tanhf(gg);
        float h2 = sigf(go)*tanhf(c2);
        C[gr*128 + hc2] = c2;
        const uint_t hb = f2b(h2);
        HLB[gr*128 + hc2] = (ushort_t)hb;
        __syncthreads();
        h2s[r*128 + hc2] = h2;
        h2b[(r*128 + hc2) ^ ((r & 7) << 3)] = (ushort_t)hb;
    }
    __syncthreads();

    // h2p on wave 0: 8 groups x 8 lanes -> rel[4][2]
    if (tid < 64) {
        const int grp = lane >> 3, sub = lane & 7;
        const int r = grp >> 1, rr = grp & 1;
        float a = 0.f;
        #pragma unroll 4
        for (int l = 0; l < 16; l++) {
            const int k = sub*16 + l;
            a += h2s[r*128 + k] * ws[F_WH2P + rr*128 + k];
        }
        a += __shfl_xor(a, 1, 64);
        a += __shfl_xor(a, 2, 64);
        a += __shfl_xor(a, 4, 64);
        if (sub == 0) {
            const float rel = a + ws[F_BH2P + rr];
            const int gr = rb + r;
            out[tstep*2048 + gr*2 + rr] = rel;
            if (do_next) LPw[gr*2 + rr] = LPr[gr*2 + rr] + rel;
            relsh[r*2 + rr] = rel;
        }
    }
    __syncthreads();

    if (!do_next) return;

    // X refresh (bf16): 4 rows x 64 cols
    if (tid < 256) {
        const int col = tid & 63, rq = tid >> 6;
        const float w0 = ws[F_WSP + col*2], w1 = ws[F_WSP + col*2 + 1], bs = ws[F_BSP + col];
        float xv = relsh[rq*2]*w0 + relsh[rq*2 + 1]*w1 + bs;
        XB[(rb + rq)*64 + col] = (ushort_t)f2b(xv);
    }

    // hp GEMM: HPw rows rb..rb+3 = h2 @ Wp1b^T + B512; 8 waves x 4 ct
    {
        const ushort_t* HPF = (const ushort_t*)(ws + OFF_HPF);
        short8v hf[4];
        #pragma unroll
        for (int kk = 0; kk < 4; kk++)
            hf[kk] = *(const short8v*)&h2b[(arow*128 + kk*32 + kch) ^ ((arow & 7) << 3)];
        #pragma unroll
        for (int ct = 0; ct < 4; ct++) {
            const int ntg = w*4 + ct;
            f32x4 acc = (f32x4){0.f,0.f,0.f,0.f};
            #pragma unroll
            for (int kk = 0; kk < 4; kk++) {
                short8v b = *(const short8v*)&HPF[((ntg*4 + kk)*64 + lane)*8];
                acc = __builtin_amdgcn_mfma_f32_16x16x32_bf16(hf[kk], b, acc, 0, 0, 0);
            }
            if (lane < 16) {
                const int col = ntg*16 + lane;
                const float bb = ws[OFF_B512 + col];
                #pragma unroll
                for (int reg = 0; reg < 4; reg++)
                    HPw[(rb + reg)*512 + col] = (ushort_t)f2b(acc[reg] + bb);
            }
        }
    }
}

// ---------------- k_lstm0: step 0, 256 blocks x 512 threads ----------------
__global__ __launch_bounds__(512) void k_lstm0(float* __restrict__ ws, float* __restrict__ out)
{
    __shared__ __align__(16) char smem[SM_BYTES];
    const int rb = blockIdx.x * 4;
    lstm_step4(ws, out, smem, rb, 0, ws + OFF_HC, rb,
               ws + OFF_LP, ws + OFF_LPB,
               (ushort_t*)(ws + OFF_HP) + 524288, 1);
}

// ---------------- k_step(t) = pool_t + mlp_t + lstm_{t+1}; 256 blocks x 512 threads ----
__global__ __launch_bounds__(512) void k_step(float* __restrict__ ws, float* __restrict__ out, int t)
{
    __shared__ __align__(16) char smem[SM_BYTES];
    const int tid = threadIdx.x;
    const int rb = blockIdx.x * 4;
    const int s  = blockIdx.x >> 3;
    const int rp = (t + 1) & 1, wp = t & 1;
    const float* LPr = ws + (rp ? OFF_LPB : OFF_LP);
    float*       LPw = ws + (wp ? OFF_LPB : OFF_LP);
    const ushort_t* HPr = (const ushort_t*)(ws + OFF_HP) + rp*524288;
    ushort_t*       HPw = (ushort_t*)(ws + OFF_HP) + wp*524288;

    const int lane = tid & 63, w = tid >> 6;        // w in 0..7
    const int arow = lane & 15, kch = (lane >> 4) * 8;

    // ======== pool phase: 4 si; scene HP in 16 VGPRs; W2F wave-slice in 64 VGPRs ========
    {
        uint_t* a1b = (uint_t*)smem;                  // R_A
        f32x4*  A2s = (f32x4*)(smem + 32768);         // R_B (256 float4)
        float*  lpS = (float*)(smem + 45184);         // R_E
        float*  php = (float*)(smem + 51584);         // R_G [4][128]
        const ushort_t* a1u = (const ushort_t*)a1b;
        const ushort_t* W2F = (const ushort_t*)(ws + OFF_W2F);

        if (tid < 64) lpS[tid] = LPr[s*64 + tid];
        if (tid < 256) A2s[tid] = ((const f32x4*)(ws + OFF_A2))[tid];

        uint2 hpreg[8];
        #pragma unroll
        for (int it = 0; it < 8; it++) {
            const int idx = tid + it*512;
            const int jl = idx >> 7, k4 = idx & 127;
            hpreg[it] = *(const uint2*)&HPr[(s*32 + jl)*512 + k4*4];
        }

        // cache this wave's W2F slice (mt = w): 16 x short8v = 64 VGPR (reused 4 q)
        short8v bw[16];
        #pragma unroll
        for (int kk = 0; kk < 16; kk++)
            bw[kk] = *(const short8v*)&W2F[((w*16 + kk)*64 + lane)*8];
        __syncthreads();

        #pragma unroll 1
        for (int q = 0; q < 4; q++) {
            const int li = ((blockIdx.x & 7) << 2) + q;     // i within scene
            const float c0 = lpS[li*2], c1 = lpS[li*2 + 1];

            #pragma unroll
            for (int it = 0; it < 8; it++) {
                const int idx = tid + it*512;
                const int jl = idx >> 7, k4 = idx & 127;
                const float r0p = lpS[jl*2] - c0, r1p = lpS[jl*2 + 1] - c1;
                const uint2 hpv = hpreg[it];
                f32x4 a0 = A2s[k4], a1v = A2s[128 + k4];
                float x  = fmaxf(blo(hpv.x) + r0p*a0[0] + r1p*a1v[0], 0.f);
                float y  = fmaxf(bhi(hpv.x) + r0p*a0[1] + r1p*a1v[1], 0.f);
                float z  = fmaxf(blo(hpv.y) + r0p*a0[2] + r1p*a1v[2], 0.f);
                float w2 = fmaxf(bhi(hpv.y) + r0p*a0[3] + r1p*a1v[3], 0.f);
                const int u = (jl*512 + k4*4) ^ ((jl & 7) << 3);
                uint2 pk;
                pk.x = f2b(x) | (f2b(y) << 16);
                pk.y = f2b(z) | (f2b(w2) << 16);
                *(uint2*)&a1b[u >> 1] = pk;
            }
            __syncthreads();

            // MFMA: wave w owns mt = w; 2 jt tiles; B from VGPR cache
            f32x4 acc[2];
            acc[0] = (f32x4){0.f,0.f,0.f,0.f};
            acc[1] = (f32x4){0.f,0.f,0.f,0.f};
            #pragma unroll 4
            for (int kk = 0; kk < 16; kk++) {
                const int kbase = kk*32 + kch;
                const int ra = arow, rb2 = 16 + arow;
                short8v a0 = *(const short8v*)&a1u[(ra *512 + kbase) ^ ((ra  & 7) << 3)];
                short8v a1f= *(const short8v*)&a1u[(rb2*512 + kbase) ^ ((rb2 & 7) << 3)];
                acc[0] = __builtin_amdgcn_mfma_f32_16x16x32_bf16(a0,  bw[kk], acc[0], 0, 0, 0);
                acc[1] = __builtin_amdgcn_mfma_f32_16x16x32_bf16(a1f, bw[kk], acc[1], 0, 0, 0);
            }

            float m0 = fmaxf(fmaxf(acc[0][0], acc[0][1]), fmaxf(acc[0][2], acc[0][3]));
            float m1 = fmaxf(fmaxf(acc[1][0], acc[1][1]), fmaxf(acc[1][2], acc[1][3]));
            float mx = fmaxf(m0, m1);
            mx = fmaxf(mx, __shfl_xor(mx, 16, 64));
            mx = fmaxf(mx, __shfl_xor(mx, 32, 64));
            if (lane < 16) {
                const int col = w*16 + lane;
                php[q*128 + col] = fmaxf(mx + ws[F_BP2 + col], 0.f);
            }
            __syncthreads();
        }
    }

    // ======== mlp phase (4 rows): hc(LDS) = relu(relu([HL|php]@Wm1^T+bm1)@Wm2^T+bm2) ====
    {
        ushort_t* at = (ushort_t*)(smem + 32768);     // R_B [16x256 swz]
        ushort_t* y1 = (ushort_t*)smem;               // R_A [16x1024 swz]
        float*    php = (float*)(smem + 51584);       // R_G (read, then overwritten by hc)
        float*    hc  = (float*)(smem + 51584);       // R_G [4][128]
        const ushort_t* HLB = (const ushort_t*)(ws + OFF_HLB);
        const ushort_t* M1F = (const ushort_t*)(ws + OFF_M1F);
        const ushort_t* M2F = (const ushort_t*)(ws + OFF_M2F);

        {   // stage [HL(bf16 copy)|php(f32 convert)]: 512 chunks, 1/thread
            const int idx = tid;
            const int r = idx >> 5, k8 = idx & 31, k = k8*8;
            uint4 val;
            if (r < 4) {
                if (k < 128) {
                    val = *(const uint4*)&HLB[(rb + r)*128 + k];   // bf16 copy
                } else {
                    const float* src = php + r*128 + (k - 128);
                    float4 f0 = ((const float4*)src)[0];
                    float4 f1 = ((const float4*)src)[1];
                    val.x = f2b(f0.x) | (f2b(f0.y) << 16);
                    val.y = f2b(f0.z) | (f2b(f0.w) << 16);
                    val.z = f2b(f1.x) | (f2b(f1.y) << 16);
                    val.w = f2b(f1.z) | (f2b(f1.w) << 16);
                }
            } else {
                val = (uint4){0u,0u,0u,0u};
            }
            *(uint4*)&at[(r*256 + k) ^ ((r & 7) << 3)] = val;
        }
        __syncthreads();

        short8v af[8];
        #pragma unroll
        for (int kk = 0; kk < 8; kk++)
            af[kk] = *(const short8v*)&at[(arow*256 + kk*32 + kch) ^ ((arow & 7) << 3)];

        // mlp1: 64 ntg over 8 waves (8 each)
        #pragma unroll 2
        for (int ct = 0; ct < 8; ct++) {
            const int ntg = w*8 + ct;
            f32x4 acc = (f32x4){0.f,0.f,0.f,0.f};
            #pragma unroll
            for (int kk = 0; kk < 8; kk++) {
                short8v b = *(const short8v*)&M1F[((ntg*8 + kk)*64 + lane)*8];
                acc = __builtin_amdgcn_mfma_f32_16x16x32_bf16(af[kk], b, acc, 0, 0, 0);
            }
            const int col = ntg*16 + (lane & 15);
            const float bb = ws[F_BM1 + col];
            const int rb4 = (lane >> 4) << 2;
            #pragma unroll
            for (int reg = 0; reg < 4; reg++) {
                const int rloc = rb4 + reg;   // rows 4-15 garbage; discarded downstream
                y1[(rloc*1024 + col) ^ ((rloc & 7) << 3)] = (ushort_t)f2b(fmaxf(acc[reg] + bb, 0.f));
            }
        }
        __syncthreads();

        // mlp2: 8 ntg over 8 waves (1 each)
        f32x4 acc2 = (f32x4){0.f,0.f,0.f,0.f};
        #pragma unroll 4
        for (int kk = 0; kk < 32; kk++) {
            short8v a = *(const short8v*)&y1[(arow*1024 + kk*32 + kch) ^ ((arow & 7) << 3)];
            short8v b = *(const short8v*)&M2F[((w*32 + kk)*64 + lane)*8];
            acc2 = __builtin_amdgcn_mfma_f32_16x16x32_bf16(a, b, acc2, 0, 0, 0);
        }
        __syncthreads();   // all php reads done before hc overwrite
        if (lane < 16) {
            const int col = w*16 + lane;
            const float bb = ws[F_BM2 + col];
            #pragma unroll
            for (int reg = 0; reg < 4; reg++)
                hc[reg*128 + col] = fmaxf(acc2[reg] + bb, 0.f);
        }
        __syncthreads();
    }

    // ======== lstm step t+1 (hc from LDS rows 0-3) ========
    lstm_step4(ws, out, smem, rb, t + 1, (const float*)(smem + 51584), 0,
               LPr, LPw, HPw, (t < T_ - 2) ? 1 : 0);
}

extern "C" void kernel_launch(void* const* d_in, const int* in_sizes, int n_in,
                              void* d_out, int out_size, void* d_ws, size_t ws_size,
                              hipStream_t stream) {
    float* ws = (float*)d_ws;
    float* out = (float*)d_out;   // reference output dtype is float32

    Ptrs ptrs;   // 22 float tensors, skipping seq_start_end (d_in[4]) and seq_len (d_in[5])
    for (int t = 0; t < 22; t++) ptrs.p[t] = d_in[t < 4 ? t : t + 2];

    k_setup<<<7070, 256, 0, stream>>>(ptrs, ws);   // conv | init | packs

    k_lstm0<<<256, 512, 0, stream>>>(ws, out);
    for (int t = 0; t < T_ - 1; t++)
        k_step<<<256, 512, 0, stream>>>(ws, out, t);
}

// Round 21
// 332.564 us; speedup vs baseline: 1.6752x; 1.6752x over previous
//
#include <hip/hip_runtime.h>
#include <hip/hip_bf16.h>
#include <math.h>

typedef unsigned short ushort_t;
typedef unsigned int uint_t;

// Problem constants: S=32 scenes, N=32 peds, B=1024, E=64, H=128, PRE=512, MLP_D=1024, T=12
// All float inputs are f32; output is f32.
#define T_ 12

// ---- ws layout (float offsets) ----
#define F_LP0   0         // last_pos      (2048)
#define F_LPR   2048      // last_pos_rel  (2048)
#define F_H0    4096      // h0            (131072)
#define F_C0    135168    // c0            (131072)
#define F_WSP   266240    // Wsp (64,2)
#define F_BSP   266368    // bsp (64)
#define F_WIH   266432    // Wih (512,64)
#define F_WHH   299200    // Whh (512,128)
#define F_BIH   364736
#define F_BHH   365248
#define F_WH2P  365760    // (2,128)
#define F_BH2P  366016    // (2)
#define F_WPE   366032    // (64,2)
#define F_BPE   366160    // (64)
#define F_WP1   366224    // (512,192)
#define F_BP1   464528    // (512)
#define F_WP2   465040    // (128,512)
#define F_BP2   530576    // (128)
#define F_WM1   530704    // (1024,256)
#define F_BM1   792848    // (1024)
#define F_WM2   793872    // (128,1024)
#define F_BM2   924944    // (128)
// State / derived (bf16 activations to keep L2 working set < 4MB/XCD):
#define OFF_HC   925072   // initial hidden f32 (B,128) [k_lstm0 read only]
#define OFF_LPB  1056144  // LP parity-1 (B,2)
#define OFF_C    1187216  // cell f32 (B,128), row-local RMW
#define OFF_XB   1318288  // lstm input bf16 (B,64) = 65536 ushorts
#define OFF_LP   1383824  // LP parity-0 (B,2)
#define OFF_HP   1385872  // HP bf16 ping-pong: 2 x (1024x512) ushorts = 524288 floats
#define OFF_A2   1910160  // (2,512)
#define OFF_B512 1911184  // (512)
#define OFF_W2F  1911696  // Wp2 bf16 B-frag pack (65536 ushorts)
#define OFF_HLB  1977232  // lstm hidden bf16 (B,128) = 131072 ushorts
#define OFF_HPF  2108304  // Wp1b B-frag pack (65536 ushorts)
#define OFF_M1F  2141072  // Wm1 B-frag pack (262144 ushorts)
#define OFF_M2F  2272144  // Wm2 B-frag pack (131072 ushorts)
#define OFF_BG   2337680  // gate bias bih+bhh (512)
#define OFF_LF   2338192  // Wih|Whh B-frag pack (98304 ushorts = 49152 floats)
// total ~2387344 floats = ~9.55 MB of d_ws

typedef __attribute__((ext_vector_type(8))) short short8v;   // 8 bf16 (4 VGPRs)
typedef __attribute__((ext_vector_type(4))) float f32x4;

__device__ __forceinline__ float sigf(float x){ return 1.0f/(1.0f+expf(-x)); }
__device__ __forceinline__ uint_t f2b(float f){  // RNE f32->bf16 (bits in low 16)
    uint_t u = __float_as_uint(f);
    return (u + 0x7FFFu + ((u >> 16) & 1u)) >> 16;
}
__device__ __forceinline__ float blo(uint_t u){ union{uint_t i; float f;} v; v.i=u<<16; return v.f; }
__device__ __forceinline__ float bhi(uint_t u){ union{uint_t i; float f;} v; v.i=u&0xffff0000u; return v.f; }

struct Ptrs { const void* p[22]; };

// ---- k_step LDS layout (59776 B); block owns 4 rows (rb = bid*4), scene s = bid>>3 ----
// 512 threads = 8 waves, 1 block/CU. NO register-array B caches (spill hazard, r14/r20).
// R_A     0..32768 : pool a1b (32x512 bf16 swz) / mlp y1 (16x1024 swz) / lstm gates (4x512 f32)
// R_B 32768..40960 : pool A2s (f32x4[256]) / mlp at (16x256 swz) / lstm h2s (4x128)
// R_C 40960..45056 : lstm h2b (16x128 bf16 swz; rows 0-3 valid)
// R_D 45056..45184 : lstm relsh (4x2 f32)
// R_E 45184..45440 : pool lpS (64 f32)
// R_F 45440..51584 : lstm atile (16x192 bf16 swz; rows 0-3 valid, rest zero)
// R_G 51584..59776 : pool php (4x128 f32) / mlp hc out (4x128 f32)
#define SM_BYTES 59776

// ---------------- merged setup: conv copy | init | B-frag packs (+A2/B512/BG) ----------------
__global__ __launch_bounds__(256) void k_setup(Ptrs ptrs, float* __restrict__ ws)
{
    const int bid = blockIdx.x, tid = threadIdx.x;

    if (bid < 3614) {   // ---- conv: copy all f32 inputs into ws ----
        const int cums[22] = {0,2048,4096,135168,266240,266368,266432,299200,364736,
                              365248,365760,366016,366018,366146,366210,464514,465026,
                              530562,530690,792834,793858,924930};
        const int dof[22]  = {F_LP0,F_LPR,F_H0,F_C0,F_WSP,F_BSP,F_WIH,F_WHH,F_BIH,F_BHH,
                              F_WH2P,F_BH2P,F_WPE,F_BPE,F_WP1,F_BP1,F_WP2,F_BP2,F_WM1,
                              F_BM1,F_WM2,F_BM2};
        const int TOTAL = 925058;
        int g = bid*256 + tid;
        if (g < TOTAL) {
            int t = 0;
            #pragma unroll
            for (int i = 1; i < 22; i++) t += (g >= cums[i]);
            int li = g - cums[t];
            ws[dof[t] + li] = ((const float*)ptrs.p[t])[li];
        }
        return;
    }
    if (bid < 4638) {   // ---- init: h,c copy; x0 (bf16); lp parity-0 ----
        const int b = bid - 3614;
        if (tid < 128) {
            ws[OFF_HC + b*128 + tid] = ((const float*)ptrs.p[2])[b*128 + tid];
            ws[OFF_C  + b*128 + tid] = ((const float*)ptrs.p[3])[b*128 + tid];
            if (tid < 64) {
                const float* lpr = (const float*)ptrs.p[1];
                const float* Wsp = (const float*)ptrs.p[4];
                const float* bsp = (const float*)ptrs.p[5];
                float p0 = lpr[b*2], p1 = lpr[b*2 + 1];
                float xv = p0*Wsp[tid*2] + p1*Wsp[tid*2+1] + bsp[tid];
                ((ushort_t*)(ws + OFF_XB))[b*64 + tid] = (ushort_t)f2b(xv);
            }
            if (tid < 2) ws[OFF_LP + b*2 + tid] = ((const float*)ptrs.p[0])[b*2 + tid];
        }
        return;
    }
    // ---- packs (+fold) ----
    const int g = (bid - 4638)*256 + tid;
    const float* Wih = (const float*)ptrs.p[6];
    const float* Whh = (const float*)ptrs.p[7];
    const float* Wp1 = (const float*)ptrs.p[14];
    if (g < 512) {      // A2/B512/BG
        const int k = g;
        const float* Wpe = (const float*)ptrs.p[12];
        const float* bpe = (const float*)ptrs.p[13];
        float a0 = 0.f, a1 = 0.f, bb = 0.f;
        for (int e = 0; e < 64; e++) {
            float w = Wp1[k*192 + e];
            a0 += Wpe[e*2 + 0] * w;
            a1 += Wpe[e*2 + 1] * w;
            bb += bpe[e]       * w;
        }
        ws[OFF_A2 + k]       = a0;
        ws[OFF_A2 + 512 + k] = a1;
        ws[OFF_B512 + k]     = bb + ((const float*)ptrs.p[15])[k];
        ws[OFF_BG + k]       = ((const float*)ptrs.p[8])[k] + ((const float*)ptrs.p[9])[k];
    }
    if (g >= 622592) return;
    const int cums[6] = {0,65536,131072,393216,524288,622592};
    int rgn = 0;
    #pragma unroll
    for (int i = 1; i < 5; i++) rgn += (g >= cums[i]);
    const int li = g - cums[rgn];
    const int Ks[5]   = {512, 128, 256, 1024, 192};
    const int strd[5] = {512, 192, 256, 1024, 0};
    const int coff[5] = {0, 64, 0, 0, 0};
    const int dst[5]  = {OFF_W2F, OFF_HPF, OFF_M1F, OFF_M2F, OFF_LF};
    const float* srcs[5] = {(const float*)ptrs.p[16], Wp1, (const float*)ptrs.p[18],
                            (const float*)ptrs.p[20], 0};
    const int K = Ks[rgn];
    const int i = li & 7, lane = (li >> 3) & 63, rest = li >> 9;
    const int nkk = K >> 5, kk = rest % nkk, nt = rest / nkk;
    const int n = nt*16 + (lane & 15);
    const int k = kk*32 + ((lane >> 4) << 3) + i;
    float v;
    if (rgn == 4) v = (k < 64) ? Wih[n*64 + k] : Whh[n*128 + (k - 64)];
    else          v = srcs[rgn][n*strd[rgn] + coff[rgn] + k];
    ((ushort_t*)(ws + dst[rgn]))[li] = (ushort_t)f2b(v);
}

// ---------------- LSTM step for 4 rows, 512 threads (8 waves split N). ----------------
// X/HL activations in bf16 (consumed only as bf16; rounding at write == at read).
__device__ void lstm_step4(float* __restrict__ ws, float* __restrict__ out, char* smem,
                           int rb, int tstep, const float* hc_base, int hc_row0,
                           const float* __restrict__ LPr, float* __restrict__ LPw,
                           ushort_t* __restrict__ HPw, int do_next)
{
    float*    gates = (float*)smem;                 // R_A [4][512]
    float*    h2s   = (float*)(smem + 32768);       // R_B [4][128]
    ushort_t* h2b   = (ushort_t*)(smem + 40960);    // R_C [16x128 swz]
    float*    relsh = (float*)(smem + 45056);       // R_D [4][2]
    ushort_t* atile = (ushort_t*)(smem + 45440);    // R_F [16x192 swz]
    const int tid = threadIdx.x;
    ushort_t* XB  = (ushort_t*)(ws + OFF_XB);
    ushort_t* HLB = (ushort_t*)(ws + OFF_HLB);
    float* C = ws + OFF_C;

    // stage A rows 0-3 = [X(64,bf16)|hc(128,f32)]; rows 4-15 zero
    if (tid < 384) {
        const int idx = tid;
        const int r = idx / 24, k8 = idx - r*24, k = k8*8;
        uint4 val;
        if (r < 4) {
            if (k < 64) {
                val = *(const uint4*)&XB[(rb + r)*64 + k];   // bf16 copy, no convert
            } else {
                const float* src = hc_base + (hc_row0 + r)*128 + (k - 64);
                float4 f0 = ((const float4*)src)[0];
                float4 f1 = ((const float4*)src)[1];
                val.x = f2b(f0.x) | (f2b(f0.y) << 16);
                val.y = f2b(f0.z) | (f2b(f0.w) << 16);
                val.z = f2b(f1.x) | (f2b(f1.y) << 16);
                val.w = f2b(f1.z) | (f2b(f1.w) << 16);
            }
        } else {
            val = (uint4){0u,0u,0u,0u};
        }
        *(uint4*)&atile[(r*192 + k) ^ ((r & 7) << 3)] = val;
    }
    __syncthreads();

    const int lane = tid & 63, w = tid >> 6;        // w in 0..7
    const int arow = lane & 15, kch = (lane >> 4) * 8;

    short8v afr[6];
    #pragma unroll
    for (int kk = 0; kk < 6; kk++)
        afr[kk] = *(const short8v*)&atile[(arow*192 + kk*32 + kch) ^ ((arow & 7) << 3)];
    __syncthreads();

    // gates MFMA: [4(pad16)][192] @ [512][192]^T, 8 waves x 4 ct
    const ushort_t* LF = (const ushort_t*)(ws + OFF_LF);
    #pragma unroll
    for (int ct = 0; ct < 4; ct++) {
        const int ntg = w*4 + ct;
        f32x4 acc = (f32x4){0.f,0.f,0.f,0.f};
        #pragma unroll
        for (int kk = 0; kk < 6; kk++) {
            short8v b = *(const short8v*)&LF[((ntg*6 + kk)*64 + lane)*8];
            acc = __builtin_amdgcn_mfma_f32_16x16x32_bf16(afr[kk], b, acc, 0, 0, 0);
        }
        if (lane < 16) {   // C rows 0-3 (row = reg)
            const int col = ntg*16 + lane;
            const float bb = ws[OFF_BG + col];
            #pragma unroll
            for (int reg = 0; reg < 4; reg++)
                gates[reg*512 + col] = acc[reg] + bb;
        }
    }
    __syncthreads();

    // pointwise: 4 rows x 128 cols = 512 items, 1/thread
    {
        const int r = tid >> 7, hc2 = tid & 127, gr = rb + r;
        float gi = gates[r*512 + hc2];
        float gf = gates[r*512 + 128 + hc2];
        float gg = gates[r*512 + 256 + hc2];
        float go = gates[r*512 + 384 + hc2];
        float c2 = sigf(gf)*C[gr*128 + hc2] + sigf(gi)*tanhf(gg);
        float h2 = sigf(go)*tanhf(c2);
        C[gr*128 + hc2] = c2;
        const uint_t hb = f2b(h2);
        HLB[gr*128 + hc2] = (ushort_t)hb;
        __syncthreads();
        h2s[r*128 + hc2] = h2;
        h2b[(r*128 + hc2) ^ ((r & 7) << 3)] = (ushort_t)hb;
    }
    __syncthreads();

    // h2p on wave 0: 8 groups x 8 lanes -> rel[4][2]
    if (tid < 64) {
        const int grp = lane >> 3, sub = lane & 7;
        const int r = grp >> 1, rr = grp & 1;
        float a = 0.f;
        #pragma unroll 4
        for (int l = 0; l < 16; l++) {
            const int k = sub*16 + l;
            a += h2s[r*128 + k] * ws[F_WH2P + rr*128 + k];
        }
        a += __shfl_xor(a, 1, 64);
        a += __shfl_xor(a, 2, 64);
        a += __shfl_xor(a, 4, 64);
        if (sub == 0) {
            const float rel = a + ws[F_BH2P + rr];
            const int gr = rb + r;
            out[tstep*2048 + gr*2 + rr] = rel;
            if (do_next) LPw[gr*2 + rr] = LPr[gr*2 + rr] + rel;
            relsh[r*2 + rr] = rel;
        }
    }
    __syncthreads();

    if (!do_next) return;

    // X refresh (bf16): 4 rows x 64 cols
    if (tid < 256) {
        const int col = tid & 63, rq = tid >> 6;
        const float w0 = ws[F_WSP + col*2], w1 = ws[F_WSP + col*2 + 1], bs = ws[F_BSP + col];
        float xv = relsh[rq*2]*w0 + relsh[rq*2 + 1]*w1 + bs;
        XB[(rb + rq)*64 + col] = (ushort_t)f2b(xv);
    }

    // hp GEMM: HPw rows rb..rb+3 = h2 @ Wp1b^T + B512; 8 waves x 4 ct
    {
        const ushort_t* HPF = (const ushort_t*)(ws + OFF_HPF);
        short8v hf[4];
        #pragma unroll
        for (int kk = 0; kk < 4; kk++)
            hf[kk] = *(const short8v*)&h2b[(arow*128 + kk*32 + kch) ^ ((arow & 7) << 3)];
        #pragma unroll
        for (int ct = 0; ct < 4; ct++) {
            const int ntg = w*4 + ct;
            f32x4 acc = (f32x4){0.f,0.f,0.f,0.f};
            #pragma unroll
            for (int kk = 0; kk < 4; kk++) {
                short8v b = *(const short8v*)&HPF[((ntg*4 + kk)*64 + lane)*8];
                acc = __builtin_amdgcn_mfma_f32_16x16x32_bf16(hf[kk], b, acc, 0, 0, 0);
            }
            if (lane < 16) {
                const int col = ntg*16 + lane;
                const float bb = ws[OFF_B512 + col];
                #pragma unroll
                for (int reg = 0; reg < 4; reg++)
                    HPw[(rb + reg)*512 + col] = (ushort_t)f2b(acc[reg] + bb);
            }
        }
    }
}

// ---------------- k_lstm0: step 0, 256 blocks x 512 threads ----------------
__global__ __launch_bounds__(512) void k_lstm0(float* __restrict__ ws, float* __restrict__ out)
{
    __shared__ __align__(16) char smem[SM_BYTES];
    const int rb = blockIdx.x * 4;
    lstm_step4(ws, out, smem, rb, 0, ws + OFF_HC, rb,
               ws + OFF_LP, ws + OFF_LPB,
               (ushort_t*)(ws + OFF_HP) + 524288, 1);
}

// ---------------- k_step(t) = pool_t + mlp_t + lstm_{t+1}; 256 blocks x 512 threads ----
__global__ __launch_bounds__(512) void k_step(float* __restrict__ ws, float* __restrict__ out, int t)
{
    __shared__ __align__(16) char smem[SM_BYTES];
    const int tid = threadIdx.x;
    const int rb = blockIdx.x * 4;
    const int s  = blockIdx.x >> 3;
    const int rp = (t + 1) & 1, wp = t & 1;
    const float* LPr = ws + (rp ? OFF_LPB : OFF_LP);
    float*       LPw = ws + (wp ? OFF_LPB : OFF_LP);
    const ushort_t* HPr = (const ushort_t*)(ws + OFF_HP) + rp*524288;
    ushort_t*       HPw = (ushort_t*)(ws + OFF_HP) + wp*524288;

    const int lane = tid & 63, w = tid >> 6;        // w in 0..7
    const int arow = lane & 15, kch = (lane >> 4) * 8;

    // ======== pool phase: 4 si; scene HP staged in 16 VGPRs; B direct from L2 ========
    {
        uint_t* a1b = (uint_t*)smem;                  // R_A
        f32x4*  A2s = (f32x4*)(smem + 32768);         // R_B (256 float4)
        float*  lpS = (float*)(smem + 45184);         // R_E
        float*  php = (float*)(smem + 51584);         // R_G [4][128]
        const ushort_t* a1u = (const ushort_t*)a1b;
        const ushort_t* W2F = (const ushort_t*)(ws + OFF_W2F);

        if (tid < 64) lpS[tid] = LPr[s*64 + tid];
        if (tid < 256) A2s[tid] = ((const f32x4*)(ws + OFF_A2))[tid];

        uint2 hpreg[8];
        #pragma unroll
        for (int it = 0; it < 8; it++) {
            const int idx = tid + it*512;
            const int jl = idx >> 7, k4 = idx & 127;
            hpreg[it] = *(const uint2*)&HPr[(s*32 + jl)*512 + k4*4];
        }
        __syncthreads();

        #pragma unroll 1
        for (int q = 0; q < 4; q++) {
            const int li = ((blockIdx.x & 7) << 2) + q;     // i within scene
            const float c0 = lpS[li*2], c1 = lpS[li*2 + 1];

            #pragma unroll
            for (int it = 0; it < 8; it++) {
                const int idx = tid + it*512;
                const int jl = idx >> 7, k4 = idx & 127;
                const float r0p = lpS[jl*2] - c0, r1p = lpS[jl*2 + 1] - c1;
                const uint2 hpv = hpreg[it];
                f32x4 a0 = A2s[k4], a1v = A2s[128 + k4];
                float x  = fmaxf(blo(hpv.x) + r0p*a0[0] + r1p*a1v[0], 0.f);
                float y  = fmaxf(bhi(hpv.x) + r0p*a0[1] + r1p*a1v[1], 0.f);
                float z  = fmaxf(blo(hpv.y) + r0p*a0[2] + r1p*a1v[2], 0.f);
                float w2 = fmaxf(bhi(hpv.y) + r0p*a0[3] + r1p*a1v[3], 0.f);
                const int u = (jl*512 + k4*4) ^ ((jl & 7) << 3);
                uint2 pk;
                pk.x = f2b(x) | (f2b(y) << 16);
                pk.y = f2b(z) | (f2b(w2) << 16);
                *(uint2*)&a1b[u >> 1] = pk;
            }
            __syncthreads();

            // MFMA: wave w owns mt = w (one 16-col tile); 2 jt tiles; B direct from L2
            f32x4 acc[2];
            acc[0] = (f32x4){0.f,0.f,0.f,0.f};
            acc[1] = (f32x4){0.f,0.f,0.f,0.f};
            #pragma unroll 4
            for (int kk = 0; kk < 16; kk++) {
                const int kbase = kk*32 + kch;
                const int ra = arow, rb2 = 16 + arow;
                short8v a0 = *(const short8v*)&a1u[(ra *512 + kbase) ^ ((ra  & 7) << 3)];
                short8v a1f= *(const short8v*)&a1u[(rb2*512 + kbase) ^ ((rb2 & 7) << 3)];
                short8v b = *(const short8v*)&W2F[((w*16 + kk)*64 + lane)*8];
                acc[0] = __builtin_amdgcn_mfma_f32_16x16x32_bf16(a0,  b, acc[0], 0, 0, 0);
                acc[1] = __builtin_amdgcn_mfma_f32_16x16x32_bf16(a1f, b, acc[1], 0, 0, 0);
            }

            float m0 = fmaxf(fmaxf(acc[0][0], acc[0][1]), fmaxf(acc[0][2], acc[0][3]));
            float m1 = fmaxf(fmaxf(acc[1][0], acc[1][1]), fmaxf(acc[1][2], acc[1][3]));
            float mx = fmaxf(m0, m1);
            mx = fmaxf(mx, __shfl_xor(mx, 16, 64));
            mx = fmaxf(mx, __shfl_xor(mx, 32, 64));
            if (lane < 16) {
                const int col = w*16 + lane;
                php[q*128 + col] = fmaxf(mx + ws[F_BP2 + col], 0.f);
            }
            __syncthreads();
        }
    }

    // ======== mlp phase (4 rows): hc(LDS) = relu(relu([HL|php]@Wm1^T+bm1)@Wm2^T+bm2) ====
    {
        ushort_t* at = (ushort_t*)(smem + 32768);     // R_B [16x256 swz]
        ushort_t* y1 = (ushort_t*)smem;               // R_A [16x1024 swz]
        float*    php = (float*)(smem + 51584);       // R_G (read, then overwritten by hc)
        float*    hc  = (float*)(smem + 51584);       // R_G [4][128]
        const ushort_t* HLB = (const ushort_t*)(ws + OFF_HLB);
        const ushort_t* M1F = (const ushort_t*)(ws + OFF_M1F);
        const ushort_t* M2F = (const ushort_t*)(ws + OFF_M2F);

        {   // stage [HL(bf16 copy)|php(f32 convert)]: 512 chunks, 1/thread
            const int idx = tid;
            const int r = idx >> 5, k8 = idx & 31, k = k8*8;
            uint4 val;
            if (r < 4) {
                if (k < 128) {
                    val = *(const uint4*)&HLB[(rb + r)*128 + k];   // bf16 copy
                } else {
                    const float* src = php + r*128 + (k - 128);
                    float4 f0 = ((const float4*)src)[0];
                    float4 f1 = ((const float4*)src)[1];
                    val.x = f2b(f0.x) | (f2b(f0.y) << 16);
                    val.y = f2b(f0.z) | (f2b(f0.w) << 16);
                    val.z = f2b(f1.x) | (f2b(f1.y) << 16);
                    val.w = f2b(f1.z) | (f2b(f1.w) << 16);
                }
            } else {
                val = (uint4){0u,0u,0u,0u};
            }
            *(uint4*)&at[(r*256 + k) ^ ((r & 7) << 3)] = val;
        }
        __syncthreads();

        short8v af[8];
        #pragma unroll
        for (int kk = 0; kk < 8; kk++)
            af[kk] = *(const short8v*)&at[(arow*256 + kk*32 + kch) ^ ((arow & 7) << 3)];

        // mlp1: 64 ntg over 8 waves (8 each)
        #pragma unroll 2
        for (int ct = 0; ct < 8; ct++) {
            const int ntg = w*8 + ct;
            f32x4 acc = (f32x4){0.f,0.f,0.f,0.f};
            #pragma unroll
            for (int kk = 0; kk < 8; kk++) {
                short8v b = *(const short8v*)&M1F[((ntg*8 + kk)*64 + lane)*8];
                acc = __builtin_amdgcn_mfma_f32_16x16x32_bf16(af[kk], b, acc, 0, 0, 0);
            }
            const int col = ntg*16 + (lane & 15);
            const float bb = ws[F_BM1 + col];
            const int rb4 = (lane >> 4) << 2;
            #pragma unroll
            for (int reg = 0; reg < 4; reg++) {
                const int rloc = rb4 + reg;   // rows 4-15 garbage; discarded downstream
                y1[(rloc*1024 + col) ^ ((rloc & 7) << 3)] = (ushort_t)f2b(fmaxf(acc[reg] + bb, 0.f));
            }
        }
        __syncthreads();

        // mlp2: 8 ntg over 8 waves (1 each)
        f32x4 acc2 = (f32x4){0.f,0.f,0.f,0.f};
        #pragma unroll 4
        for (int kk = 0; kk < 32; kk++) {
            short8v a = *(const short8v*)&y1[(arow*1024 + kk*32 + kch) ^ ((arow & 7) << 3)];
            short8v b = *(const short8v*)&M2F[((w*32 + kk)*64 + lane)*8];
            acc2 = __builtin_amdgcn_mfma_f32_16x16x32_bf16(a, b, acc2, 0, 0, 0);
        }
        __syncthreads();   // all php reads done before hc overwrite
        if (lane < 16) {
            const int col = w*16 + lane;
            const float bb = ws[F_BM2 + col];
            #pragma unroll
            for (int reg = 0; reg < 4; reg++)
                hc[reg*128 + col] = fmaxf(acc2[reg] + bb, 0.f);
        }
        __syncthreads();
    }

    // ======== lstm step t+1 (hc from LDS rows 0-3) ========
    lstm_step4(ws, out, smem, rb, t + 1, (const float*)(smem + 51584), 0,
               LPr, LPw, HPw, (t < T_ - 2) ? 1 : 0);
}

extern "C" void kernel_launch(void* const* d_in, const int* in_sizes, int n_in,
                              void* d_out, int out_size, void* d_ws, size_t ws_size,
                              hipStream_t stream) {
    float* ws = (float*)d_ws;
    float* out = (float*)d_out;   // reference output dtype is float32

    Ptrs ptrs;   // 22 float tensors, skipping seq_start_end (d_in[4]) and seq_len (d_in[5])
    for (int t = 0; t < 22; t++) ptrs.p[t] = d_in[t < 4 ? t : t + 2];

    k_setup<<<7070, 256, 0, stream>>>(ptrs, ws);   // conv | init | packs

    k_lstm0<<<256, 512, 0, stream>>>(ws, out);
    for (int t = 0; t < T_ - 1; t++)
        k_step<<<256, 512, 0, stream>>>(ws, out, t);
}

// Round 22
// 330.760 us; speedup vs baseline: 1.6844x; 1.0055x over previous
//
#include <hip/hip_runtime.h>
#include <hip/hip_bf16.h>
#include <math.h>

typedef unsigned short ushort_t;
typedef unsigned int uint_t;

// Problem constants: S=32 scenes, N=32 peds, B=1024, E=64, H=128, PRE=512, MLP_D=1024, T=12
// All float inputs are f32; output is f32.
#define T_ 12

// ---- ws layout (float offsets) ----
// (F_* slots for raw-input copies are retained for layout stability; only the
//  7 small tensors actually consumed as f32 by run kernels are copied.)
#define F_WSP   266240    // Wsp (64,2)
#define F_BSP   266368    // bsp (64)
#define F_WH2P  365760    // (2,128)
#define F_BH2P  366016    // (2)
#define F_BP2   530576    // (128)
#define F_BM1   792848    // (1024)
#define F_BM2   924944    // (128)
// State / derived:
#define OFF_HC   925072   // initial hidden f32 (B,128) [k_lstm0 read only]
#define OFF_LPB  1056144  // LP parity-1 (B,2)
#define OFF_C    1187216  // cell f32 (B,128), row-local RMW
#define OFF_XB   1318288  // lstm input bf16 (B,64) = 65536 ushorts
#define OFF_LP   1383824  // LP parity-0 (B,2)
#define OFF_HP   1385872  // HP bf16 ping-pong: 2 x (1024x512) ushorts = 524288 floats
#define OFF_A2   1910160  // (2,512)
#define OFF_B512 1911184  // (512)
#define OFF_W2F  1911696  // Wp2 bf16 B-frag pack (65536 ushorts)
#define OFF_HLB  1977232  // lstm hidden bf16 (B,128) = 131072 ushorts
#define OFF_HPF  2108304  // Wp1b B-frag pack (65536 ushorts)
#define OFF_M1F  2141072  // Wm1 B-frag pack (262144 ushorts)
#define OFF_M2F  2272144  // Wm2 B-frag pack (131072 ushorts)
#define OFF_BG   2337680  // gate bias bih+bhh (512)
#define OFF_LF   2338192  // Wih|Whh B-frag pack (98304 ushorts = 49152 floats)
// total ~2387344 floats = ~9.55 MB of d_ws

typedef __attribute__((ext_vector_type(8))) short short8v;   // 8 bf16 (4 VGPRs)
typedef __attribute__((ext_vector_type(4))) float f32x4;

__device__ __forceinline__ float sigf(float x){ return 1.0f/(1.0f+expf(-x)); }
__device__ __forceinline__ uint_t f2b(float f){  // RNE f32->bf16 (bits in low 16)
    uint_t u = __float_as_uint(f);
    return (u + 0x7FFFu + ((u >> 16) & 1u)) >> 16;
}
__device__ __forceinline__ float blo(uint_t u){ union{uint_t i; float f;} v; v.i=u<<16; return v.f; }
__device__ __forceinline__ float bhi(uint_t u){ union{uint_t i; float f;} v; v.i=u&0xffff0000u; return v.f; }

struct Ptrs { const void* p[22]; };

// ---- k_step LDS layout (59776 B); block owns 4 rows (rb = bid*4), scene s = bid>>3 ----
// 512 threads = 8 waves, 1 block/CU. NO register-array B caches (spill hazard, r14/r20).
#define SM_BYTES 59776

// ---------------- merged setup: small-const copies | init | B-frag packs (+A2/B512/BG) ----
// Dead bulk copies removed (r22): run kernels read only 1730 f32 consts from ws.
__global__ __launch_bounds__(256) void k_setup(Ptrs ptrs, float* __restrict__ ws)
{
    const int bid = blockIdx.x, tid = threadIdx.x;

    if (bid < 7) {   // ---- copy the 7 small f32 tensors consumed by run kernels ----
        const int cums[8] = {0,128,192,448,450,578,1602,1730};
        const int srcs[7] = {4,5,10,11,17,19,21};
        const int dsts[7] = {F_WSP,F_BSP,F_WH2P,F_BH2P,F_BP2,F_BM1,F_BM2};
        int g = bid*256 + tid;
        if (g < 1730) {
            int t = 0;
            #pragma unroll
            for (int i = 1; i < 7; i++) t += (g >= cums[i]);
            int li = g - cums[t];
            ws[dsts[t] + li] = ((const float*)ptrs.p[srcs[t]])[li];
        }
        return;
    }
    if (bid < 1031) {   // ---- init: h,c copy; x0 (bf16); lp parity-0 (raw inputs) ----
        const int b = bid - 7;
        if (tid < 128) {
            ws[OFF_HC + b*128 + tid] = ((const float*)ptrs.p[2])[b*128 + tid];
            ws[OFF_C  + b*128 + tid] = ((const float*)ptrs.p[3])[b*128 + tid];
            if (tid < 64) {
                const float* lpr = (const float*)ptrs.p[1];
                const float* Wsp = (const float*)ptrs.p[4];
                const float* bsp = (const float*)ptrs.p[5];
                float p0 = lpr[b*2], p1 = lpr[b*2 + 1];
                float xv = p0*Wsp[tid*2] + p1*Wsp[tid*2+1] + bsp[tid];
                ((ushort_t*)(ws + OFF_XB))[b*64 + tid] = (ushort_t)f2b(xv);
            }
            if (tid < 2) ws[OFF_LP + b*2 + tid] = ((const float*)ptrs.p[0])[b*2 + tid];
        }
        return;
    }
    // ---- packs (+fold): read raw inputs ----
    const int g = (bid - 1031)*256 + tid;
    const float* Wih = (const float*)ptrs.p[6];
    const float* Whh = (const float*)ptrs.p[7];
    const float* Wp1 = (const float*)ptrs.p[14];
    if (g < 512) {      // A2/B512/BG
        const int k = g;
        const float* Wpe = (const float*)ptrs.p[12];
        const float* bpe = (const float*)ptrs.p[13];
        float a0 = 0.f, a1 = 0.f, bb = 0.f;
        for (int e = 0; e < 64; e++) {
            float w = Wp1[k*192 + e];
            a0 += Wpe[e*2 + 0] * w;
            a1 += Wpe[e*2 + 1] * w;
            bb += bpe[e]       * w;
        }
        ws[OFF_A2 + k]       = a0;
        ws[OFF_A2 + 512 + k] = a1;
        ws[OFF_B512 + k]     = bb + ((const float*)ptrs.p[15])[k];
        ws[OFF_BG + k]       = ((const float*)ptrs.p[8])[k] + ((const float*)ptrs.p[9])[k];
    }
    if (g >= 622592) return;
    const int cums[6] = {0,65536,131072,393216,524288,622592};
    int rgn = 0;
    #pragma unroll
    for (int i = 1; i < 5; i++) rgn += (g >= cums[i]);
    const int li = g - cums[rgn];
    const int Ks[5]   = {512, 128, 256, 1024, 192};
    const int strd[5] = {512, 192, 256, 1024, 0};
    const int coff[5] = {0, 64, 0, 0, 0};
    const int dst[5]  = {OFF_W2F, OFF_HPF, OFF_M1F, OFF_M2F, OFF_LF};
    const float* srcs[5] = {(const float*)ptrs.p[16], Wp1, (const float*)ptrs.p[18],
                            (const float*)ptrs.p[20], 0};
    const int K = Ks[rgn];
    const int i = li & 7, lane = (li >> 3) & 63, rest = li >> 9;
    const int nkk = K >> 5, kk = rest % nkk, nt = rest / nkk;
    const int n = nt*16 + (lane & 15);
    const int k = kk*32 + ((lane >> 4) << 3) + i;
    float v;
    if (rgn == 4) v = (k < 64) ? Wih[n*64 + k] : Whh[n*128 + (k - 64)];
    else          v = srcs[rgn][n*strd[rgn] + coff[rgn] + k];
    ((ushort_t*)(ws + dst[rgn]))[li] = (ushort_t)f2b(v);
}

// ---------------- LSTM step for 4 rows, 512 threads (8 waves split N). ----------------
__device__ void lstm_step4(float* __restrict__ ws, float* __restrict__ out, char* smem,
                           int rb, int tstep, const float* hc_base, int hc_row0,
                           const float* __restrict__ LPr, float* __restrict__ LPw,
                           ushort_t* __restrict__ HPw, int do_next)
{
    float*    gates = (float*)smem;                 // R_A [4][512]
    float*    h2s   = (float*)(smem + 32768);       // R_B [4][128]
    ushort_t* h2b   = (ushort_t*)(smem + 40960);    // R_C [16x128 swz]
    float*    relsh = (float*)(smem + 45056);       // R_D [4][2]
    ushort_t* atile = (ushort_t*)(smem + 45440);    // R_F [16x192 swz]
    const int tid = threadIdx.x;
    ushort_t* XB  = (ushort_t*)(ws + OFF_XB);
    ushort_t* HLB = (ushort_t*)(ws + OFF_HLB);
    float* C = ws + OFF_C;

    // stage A rows 0-3 = [X(64,bf16)|hc(128,f32)]; rows 4-15 zero
    if (tid < 384) {
        const int idx = tid;
        const int r = idx / 24, k8 = idx - r*24, k = k8*8;
        uint4 val;
        if (r < 4) {
            if (k < 64) {
                val = *(const uint4*)&XB[(rb + r)*64 + k];   // bf16 copy, no convert
            } else {
                const float* src = hc_base + (hc_row0 + r)*128 + (k - 64);
                float4 f0 = ((const float4*)src)[0];
                float4 f1 = ((const float4*)src)[1];
                val.x = f2b(f0.x) | (f2b(f0.y) << 16);
                val.y = f2b(f0.z) | (f2b(f0.w) << 16);
                val.z = f2b(f1.x) | (f2b(f1.y) << 16);
                val.w = f2b(f1.z) | (f2b(f1.w) << 16);
            }
        } else {
            val = (uint4){0u,0u,0u,0u};
        }
        *(uint4*)&atile[(r*192 + k) ^ ((r & 7) << 3)] = val;
    }
    __syncthreads();

    const int lane = tid & 63, w = tid >> 6;        // w in 0..7
    const int arow = lane & 15, kch = (lane >> 4) * 8;

    short8v afr[6];
    #pragma unroll
    for (int kk = 0; kk < 6; kk++)
        afr[kk] = *(const short8v*)&atile[(arow*192 + kk*32 + kch) ^ ((arow & 7) << 3)];
    __syncthreads();

    // gates MFMA: [4(pad16)][192] @ [512][192]^T, 8 waves x 4 ct
    const ushort_t* LF = (const ushort_t*)(ws + OFF_LF);
    #pragma unroll
    for (int ct = 0; ct < 4; ct++) {
        const int ntg = w*4 + ct;
        f32x4 acc = (f32x4){0.f,0.f,0.f,0.f};
        #pragma unroll
        for (int kk = 0; kk < 6; kk++) {
            short8v b = *(const short8v*)&LF[((ntg*6 + kk)*64 + lane)*8];
            acc = __builtin_amdgcn_mfma_f32_16x16x32_bf16(afr[kk], b, acc, 0, 0, 0);
        }
        if (lane < 16) {   // C rows 0-3 (row = reg)
            const int col = ntg*16 + lane;
            const float bb = ws[OFF_BG + col];
            #pragma unroll
            for (int reg = 0; reg < 4; reg++)
                gates[reg*512 + col] = acc[reg] + bb;
        }
    }
    __syncthreads();

    // pointwise: 4 rows x 128 cols = 512 items, 1/thread
    {
        const int r = tid >> 7, hc2 = tid & 127, gr = rb + r;
        float gi = gates[r*512 + hc2];
        float gf = gates[r*512 + 128 + hc2];
        float gg = gates[r*512 + 256 + hc2];
        float go = gates[r*512 + 384 + hc2];
        float c2 = sigf(gf)*C[gr*128 + hc2] + sigf(gi)*tanhf(gg);
        float h2 = sigf(go)*tanhf(c2);
        C[gr*128 + hc2] = c2;
        const uint_t hb = f2b(h2);
        HLB[gr*128 + hc2] = (ushort_t)hb;
        __syncthreads();
        h2s[r*128 + hc2] = h2;
        h2b[(r*128 + hc2) ^ ((r & 7) << 3)] = (ushort_t)hb;
    }
    __syncthreads();

    // h2p on wave 0: 8 groups x 8 lanes -> rel[4][2]
    if (tid < 64) {
        const int grp = lane >> 3, sub = lane & 7;
        const int r = grp >> 1, rr = grp & 1;
        float a = 0.f;
        #pragma unroll 4
        for (int l = 0; l < 16; l++) {
            const int k = sub*16 + l;
            a += h2s[r*128 + k] * ws[F_WH2P + rr*128 + k];
        }
        a += __shfl_xor(a, 1, 64);
        a += __shfl_xor(a, 2, 64);
        a += __shfl_xor(a, 4, 64);
        if (sub == 0) {
            const float rel = a + ws[F_BH2P + rr];
            const int gr = rb + r;
            out[tstep*2048 + gr*2 + rr] = rel;
            if (do_next) LPw[gr*2 + rr] = LPr[gr*2 + rr] + rel;
            relsh[r*2 + rr] = rel;
        }
    }
    __syncthreads();

    if (!do_next) return;

    // X refresh (bf16): 4 rows x 64 cols
    if (tid < 256) {
        const int col = tid & 63, rq = tid >> 6;
        const float w0 = ws[F_WSP + col*2], w1 = ws[F_WSP + col*2 + 1], bs = ws[F_BSP + col];
        float xv = relsh[rq*2]*w0 + relsh[rq*2 + 1]*w1 + bs;
        XB[(rb + rq)*64 + col] = (ushort_t)f2b(xv);
    }

    // hp GEMM: HPw rows rb..rb+3 = h2 @ Wp1b^T + B512; 8 waves x 4 ct
    {
        const ushort_t* HPF = (const ushort_t*)(ws + OFF_HPF);
        short8v hf[4];
        #pragma unroll
        for (int kk = 0; kk < 4; kk++)
            hf[kk] = *(const short8v*)&h2b[(arow*128 + kk*32 + kch) ^ ((arow & 7) << 3)];
        #pragma unroll
        for (int ct = 0; ct < 4; ct++) {
            const int ntg = w*4 + ct;
            f32x4 acc = (f32x4){0.f,0.f,0.f,0.f};
            #pragma unroll
            for (int kk = 0; kk < 4; kk++) {
                short8v b = *(const short8v*)&HPF[((ntg*4 + kk)*64 + lane)*8];
                acc = __builtin_amdgcn_mfma_f32_16x16x32_bf16(hf[kk], b, acc, 0, 0, 0);
            }
            if (lane < 16) {
                const int col = ntg*16 + lane;
                const float bb = ws[OFF_B512 + col];
                #pragma unroll
                for (int reg = 0; reg < 4; reg++)
                    HPw[(rb + reg)*512 + col] = (ushort_t)f2b(acc[reg] + bb);
            }
        }
    }
}

// ---------------- k_lstm0: step 0, 256 blocks x 512 threads ----------------
__global__ __launch_bounds__(512) void k_lstm0(float* __restrict__ ws, float* __restrict__ out)
{
    __shared__ __align__(16) char smem[SM_BYTES];
    const int rb = blockIdx.x * 4;
    lstm_step4(ws, out, smem, rb, 0, ws + OFF_HC, rb,
               ws + OFF_LP, ws + OFF_LPB,
               (ushort_t*)(ws + OFF_HP) + 524288, 1);
}

// ---------------- k_step(t) = pool_t + mlp_t + lstm_{t+1}; 256 blocks x 512 threads ----
__global__ __launch_bounds__(512) void k_step(float* __restrict__ ws, float* __restrict__ out, int t)
{
    __shared__ __align__(16) char smem[SM_BYTES];
    const int tid = threadIdx.x;
    const int rb = blockIdx.x * 4;
    const int s  = blockIdx.x >> 3;
    const int rp = (t + 1) & 1, wp = t & 1;
    const float* LPr = ws + (rp ? OFF_LPB : OFF_LP);
    float*       LPw = ws + (wp ? OFF_LPB : OFF_LP);
    const ushort_t* HPr = (const ushort_t*)(ws + OFF_HP) + rp*524288;
    ushort_t*       HPw = (ushort_t*)(ws + OFF_HP) + wp*524288;

    const int lane = tid & 63, w = tid >> 6;        // w in 0..7
    const int arow = lane & 15, kch = (lane >> 4) * 8;

    // ======== pool phase: 4 si; scene HP staged in 16 VGPRs; B direct from L2 ========
    {
        uint_t* a1b = (uint_t*)smem;                  // R_A
        f32x4*  A2s = (f32x4*)(smem + 32768);         // R_B (256 float4)
        float*  lpS = (float*)(smem + 45184);         // R_E
        float*  php = (float*)(smem + 51584);         // R_G [4][128]
        const ushort_t* a1u = (const ushort_t*)a1b;
        const ushort_t* W2F = (const ushort_t*)(ws + OFF_W2F);

        if (tid < 64) lpS[tid] = LPr[s*64 + tid];
        if (tid < 256) A2s[tid] = ((const f32x4*)(ws + OFF_A2))[tid];

        uint2 hpreg[8];
        #pragma unroll
        for (int it = 0; it < 8; it++) {
            const int idx = tid + it*512;
            const int jl = idx >> 7, k4 = idx & 127;
            hpreg[it] = *(const uint2*)&HPr[(s*32 + jl)*512 + k4*4];
        }
        __syncthreads();

        #pragma unroll 1
        for (int q = 0; q < 4; q++) {
            const int li = ((blockIdx.x & 7) << 2) + q;     // i within scene
            const float c0 = lpS[li*2], c1 = lpS[li*2 + 1];

            #pragma unroll
            for (int it = 0; it < 8; it++) {
                const int idx = tid + it*512;
                const int jl = idx >> 7, k4 = idx & 127;
                const float r0p = lpS[jl*2] - c0, r1p = lpS[jl*2 + 1] - c1;
                const uint2 hpv = hpreg[it];
                f32x4 a0 = A2s[k4], a1v = A2s[128 + k4];
                float x  = fmaxf(blo(hpv.x) + r0p*a0[0] + r1p*a1v[0], 0.f);
                float y  = fmaxf(bhi(hpv.x) + r0p*a0[1] + r1p*a1v[1], 0.f);
                float z  = fmaxf(blo(hpv.y) + r0p*a0[2] + r1p*a1v[2], 0.f);
                float w2 = fmaxf(bhi(hpv.y) + r0p*a0[3] + r1p*a1v[3], 0.f);
                const int u = (jl*512 + k4*4) ^ ((jl & 7) << 3);
                uint2 pk;
                pk.x = f2b(x) | (f2b(y) << 16);
                pk.y = f2b(z) | (f2b(w2) << 16);
                *(uint2*)&a1b[u >> 1] = pk;
            }
            __syncthreads();

            // MFMA: wave w owns mt = w (one 16-col tile); 2 jt tiles; B direct from L2
            f32x4 acc[2];
            acc[0] = (f32x4){0.f,0.f,0.f,0.f};
            acc[1] = (f32x4){0.f,0.f,0.f,0.f};
            #pragma unroll 4
            for (int kk = 0; kk < 16; kk++) {
                const int kbase = kk*32 + kch;
                const int ra = arow, rb2 = 16 + arow;
                short8v a0 = *(const short8v*)&a1u[(ra *512 + kbase) ^ ((ra  & 7) << 3)];
                short8v a1f= *(const short8v*)&a1u[(rb2*512 + kbase) ^ ((rb2 & 7) << 3)];
                short8v b = *(const short8v*)&W2F[((w*16 + kk)*64 + lane)*8];
                acc[0] = __builtin_amdgcn_mfma_f32_16x16x32_bf16(a0,  b, acc[0], 0, 0, 0);
                acc[1] = __builtin_amdgcn_mfma_f32_16x16x32_bf16(a1f, b, acc[1], 0, 0, 0);
            }

            float m0 = fmaxf(fmaxf(acc[0][0], acc[0][1]), fmaxf(acc[0][2], acc[0][3]));
            float m1 = fmaxf(fmaxf(acc[1][0], acc[1][1]), fmaxf(acc[1][2], acc[1][3]));
            float mx = fmaxf(m0, m1);
            mx = fmaxf(mx, __shfl_xor(mx, 16, 64));
            mx = fmaxf(mx, __shfl_xor(mx, 32, 64));
            if (lane < 16) {
                const int col = w*16 + lane;
                php[q*128 + col] = fmaxf(mx + ws[F_BP2 + col], 0.f);
            }
            __syncthreads();
        }
    }

    // ======== mlp phase (4 rows): hc(LDS) = relu(relu([HL|php]@Wm1^T+bm1)@Wm2^T+bm2) ====
    {
        ushort_t* at = (ushort_t*)(smem + 32768);     // R_B [16x256 swz]
        ushort_t* y1 = (ushort_t*)smem;               // R_A [16x1024 swz]
        float*    php = (float*)(smem + 51584);       // R_G (read, then overwritten by hc)
        float*    hc  = (float*)(smem + 51584);       // R_G [4][128]
        const ushort_t* HLB = (const ushort_t*)(ws + OFF_HLB);
        const ushort_t* M1F = (const ushort_t*)(ws + OFF_M1F);
        const ushort_t* M2F = (const ushort_t*)(ws + OFF_M2F);

        {   // stage [HL(bf16 copy)|php(f32 convert)]: 512 chunks, 1/thread
            const int idx = tid;
            const int r = idx >> 5, k8 = idx & 31, k = k8*8;
            uint4 val;
            if (r < 4) {
                if (k < 128) {
                    val = *(const uint4*)&HLB[(rb + r)*128 + k];   // bf16 copy
                } else {
                    const float* src = php + r*128 + (k - 128);
                    float4 f0 = ((const float4*)src)[0];
                    float4 f1 = ((const float4*)src)[1];
                    val.x = f2b(f0.x) | (f2b(f0.y) << 16);
                    val.y = f2b(f0.z) | (f2b(f0.w) << 16);
                    val.z = f2b(f1.x) | (f2b(f1.y) << 16);
                    val.w = f2b(f1.z) | (f2b(f1.w) << 16);
                }
            } else {
                val = (uint4){0u,0u,0u,0u};
            }
            *(uint4*)&at[(r*256 + k) ^ ((r & 7) << 3)] = val;
        }
        __syncthreads();

        short8v af[8];
        #pragma unroll
        for (int kk = 0; kk < 8; kk++)
            af[kk] = *(const short8v*)&at[(arow*256 + kk*32 + kch) ^ ((arow & 7) << 3)];

        // mlp1: 64 ntg over 8 waves (8 each)
        #pragma unroll 2
        for (int ct = 0; ct < 8; ct++) {
            const int ntg = w*8 + ct;
            f32x4 acc = (f32x4){0.f,0.f,0.f,0.f};
            #pragma unroll
            for (int kk = 0; kk < 8; kk++) {
                short8v b = *(const short8v*)&M1F[((ntg*8 + kk)*64 + lane)*8];
                acc = __builtin_amdgcn_mfma_f32_16x16x32_bf16(af[kk], b, acc, 0, 0, 0);
            }
            const int col = ntg*16 + (lane & 15);
            const float bb = ws[F_BM1 + col];
            const int rb4 = (lane >> 4) << 2;
            #pragma unroll
            for (int reg = 0; reg < 4; reg++) {
                const int rloc = rb4 + reg;   // rows 4-15 garbage; discarded downstream
                y1[(rloc*1024 + col) ^ ((rloc & 7) << 3)] = (ushort_t)f2b(fmaxf(acc[reg] + bb, 0.f));
            }
        }
        __syncthreads();

        // mlp2: 8 ntg over 8 waves (1 each)
        f32x4 acc2 = (f32x4){0.f,0.f,0.f,0.f};
        #pragma unroll 4
        for (int kk = 0; kk < 32; kk++) {
            short8v a = *(const short8v*)&y1[(arow*1024 + kk*32 + kch) ^ ((arow & 7) << 3)];
            short8v b = *(const short8v*)&M2F[((w*32 + kk)*64 + lane)*8];
            acc2 = __builtin_amdgcn_mfma_f32_16x16x32_bf16(a, b, acc2, 0, 0, 0);
        }
        __syncthreads();   // all php reads done before hc overwrite
        if (lane < 16) {
            const int col = w*16 + lane;
            const float bb = ws[F_BM2 + col];
            #pragma unroll
            for (int reg = 0; reg < 4; reg++)
                hc[reg*128 + col] = fmaxf(acc2[reg] + bb, 0.f);
        }
        __syncthreads();
    }

    // ======== lstm step t+1 (hc from LDS rows 0-3) ========
    lstm_step4(ws, out, smem, rb, t + 1, (const float*)(smem + 51584), 0,
               LPr, LPw, HPw, (t < T_ - 2) ? 1 : 0);
}

extern "C" void kernel_launch(void* const* d_in, const int* in_sizes, int n_in,
                              void* d_out, int out_size, void* d_ws, size_t ws_size,
                              hipStream_t stream) {
    float* ws = (float*)d_ws;
    float* out = (float*)d_out;   // reference output dtype is float32

    Ptrs ptrs;   // 22 float tensors, skipping seq_start_end (d_in[4]) and seq_len (d_in[5])
    for (int t = 0; t < 22; t++) ptrs.p[t] = d_in[t < 4 ? t : t + 2];

    k_setup<<<3463, 256, 0, stream>>>(ptrs, ws);   // consts | init | packs

    k_lstm0<<<256, 512, 0, stream>>>(ws, out);
    for (int t = 0; t < T_ - 1; t++)
        k_step<<<256, 512, 0, stream>>>(ws, out, t);
}